// Round 6
// baseline (403.714 us; speedup 1.0000x reference)
//
#include <hip/hip_runtime.h>
#include <math.h>

// Problem constants
#define NN       16384
#define IN_DIM   64
#define CC       4
#define NMAT     (NN * CC)           // 65536 matrices
#define ROWF     36                  // floats per LDS row (16 complex + 2 pad)
#define BUFW     (16 * ROWF)         // 576 floats per buffer
#define MWORDS   (BUFW + 4)          // 580 floats per matrix region (4-bank stagger)
#define MPB      8                   // matrices per block (128 threads, 2 waves)

// Taylor coefficients 1/k!
#define C0 1.0f
#define C1 1.0f
#define C2 0.5f
#define C3 0.16666666666666666f
#define C4 0.041666666666666664f
#define C5 0.008333333333333333f
#define C6 0.001388888888888889f
#define C7 1.984126984126984e-4f
#define C8 2.48015873015873e-5f

// ---------------------------------------------------------------------------
// Phase 1 (ws path): B[n,c,i,j] = sum_k dX[n,k] * (Ar + i*Ai)[k,c,i,j]
// 8 n's per thread -> A-row loads amortized 8x. Fully coalesced stores.
// ---------------------------------------------------------------------------
__global__ __launch_bounds__(256)
void ax_kernel(const float* __restrict__ dX, const float* __restrict__ Ar,
               const float* __restrict__ Ai, float* __restrict__ ws)
{
    const int t  = threadIdx.x;
    const int nb = blockIdx.x * 8;         // 8 n's per block
    const int c  = t >> 6;
    const int i  = (t >> 2) & 15;
    const int j0 = (t & 3) * 4;

    float accre[8][4], accim[8][4];
#pragma unroll
    for (int nn_ = 0; nn_ < 8; ++nn_)
#pragma unroll
        for (int jj = 0; jj < 4; ++jj) { accre[nn_][jj] = 0.f; accim[nn_][jj] = 0.f; }

#pragma unroll 2
    for (int k = 0; k < IN_DIM; ++k) {
        const int base = (k * CC + c) * 256 + i * 16 + j0;
        const float4 ar = *reinterpret_cast<const float4*>(Ar + base);
        const float4 ai = *reinterpret_cast<const float4*>(Ai + base);
#pragma unroll
        for (int nn_ = 0; nn_ < 8; ++nn_) {
            const float dxv = dX[(nb + nn_) * IN_DIM + k];  // block-uniform -> s_load
#pragma unroll
            for (int jj = 0; jj < 4; ++jj) {
                accre[nn_][jj] = fmaf(dxv, (&ar.x)[jj], accre[nn_][jj]);
                accim[nn_][jj] = fmaf(dxv, (&ai.x)[jj], accim[nn_][jj]);
            }
        }
    }
#pragma unroll
    for (int nn_ = 0; nn_ < 8; ++nn_) {
        const int m = (nb + nn_) * CC + c;
        float* o = ws + (size_t)m * 512 + (i * 16 + j0) * 2;
        reinterpret_cast<float4*>(o)[0] =
            make_float4(accre[nn_][0], accim[nn_][0], accre[nn_][1], accim[nn_][1]);
        reinterpret_cast<float4*>(o)[1] =
            make_float4(accre[nn_][2], accim[nn_][2], accre[nn_][3], accim[nn_][3]);
    }
}

// ---------------------------------------------------------------------------
// Phase 2: per 16x16 complex matrix: skew-projection, 1-norm -> s, scale,
// expm via Paterson-Stockmeyer degree-8 (4 matmuls), then s squarings.
// One matrix per 16-lane group, 4x4 complex tile per lane. Single LDS buffer
// per matrix; Z in registers, Horner Y-operand via __shfl.
// waves_per_eu(4,4): pin allocator budget to 128 VGPR (round-5 squeezed to
// 64 and spilled ~280 MB of scratch traffic). Per-kk matmul granularity
// keeps live temps ~16 floats so 128 fits without spills.
// All LDS traffic is per-lane-distinct and same-wave ordered (no barriers).
// ---------------------------------------------------------------------------
__attribute__((amdgpu_waves_per_eu(4, 4)))
__global__ void __launch_bounds__(128)
expm_kernel(const float* __restrict__ dX, const float* __restrict__ Ar,
            const float* __restrict__ Ai, const float* __restrict__ ws,
            float* __restrict__ out, const int use_ws, const int real_only)
{
    __shared__ __align__(16) float lds[MPB * MWORDS];

    const int t   = threadIdx.x;
    const int grp = t >> 4;
    const int sub = t & 15;
    const int si  = sub >> 2, sj = sub & 3;
    const int i0  = si * 4,  j0 = sj * 4;

    float* buf0 = lds + grp * MWORDS;   // the single per-matrix buffer

    const int m = blockIdx.x * MPB + grp;
    const int n = m >> 2;
    const int c = m & 3;

    // ---- obtain skew tile a[r][jj] = AX[i0+r, j0+jj] = 0.5*(B[i,j] - conj(B[j,i]))
    float2 a[4][4];
    if (use_ws) {
        const float* g = ws + (size_t)m * 512;
        float bs[4][8];   // straight rows:   bs[r][2t+e] = B[i0+r, j0+t].{re,im}
        float wf[4][8];   // transposed rows: wf[r][2t+e] = B[j0+r, i0+t].{re,im}
#pragma unroll
        for (int r = 0; r < 4; ++r) {
            *reinterpret_cast<float4*>(&bs[r][0]) =
                reinterpret_cast<const float4*>(g + ((i0 + r) * 16 + j0) * 2)[0];
            *reinterpret_cast<float4*>(&bs[r][4]) =
                reinterpret_cast<const float4*>(g + ((i0 + r) * 16 + j0) * 2)[1];
            *reinterpret_cast<float4*>(&wf[r][0]) =
                reinterpret_cast<const float4*>(g + ((j0 + r) * 16 + i0) * 2)[0];
            *reinterpret_cast<float4*>(&wf[r][4]) =
                reinterpret_cast<const float4*>(g + ((j0 + r) * 16 + i0) * 2)[1];
        }
        // register-only transpose: B[j0+jj, i0+r] = wf[jj][2r+e]  (compile-time idx)
#pragma unroll
        for (int r = 0; r < 4; ++r)
#pragma unroll
            for (int jj = 0; jj < 4; ++jj) {
                a[r][jj].x = 0.5f * (bs[r][2 * jj]     - wf[jj][2 * r]);
                a[r][jj].y = 0.5f * (bs[r][2 * jj + 1] + wf[jj][2 * r + 1]);
            }
    } else {
        // fused fallback: inline einsum for B tile + LDS transpose (per-lane-distinct)
        float2 b[4][4];
#pragma unroll
        for (int r = 0; r < 4; ++r)
#pragma unroll
            for (int jj = 0; jj < 4; ++jj) b[r][jj] = make_float2(0.f, 0.f);
        const float* dxp = dX + n * IN_DIM;
#pragma unroll 2
        for (int k = 0; k < IN_DIM; ++k) {
            const float dxv = dxp[k];
            const int base = (k * CC + c) * 256 + i0 * 16 + j0;
#pragma unroll
            for (int r = 0; r < 4; ++r) {
                const float4 ar = *reinterpret_cast<const float4*>(Ar + base + r * 16);
                const float4 ai = *reinterpret_cast<const float4*>(Ai + base + r * 16);
#pragma unroll
                for (int jj = 0; jj < 4; ++jj) {
                    b[r][jj].x = fmaf(dxv, (&ar.x)[jj], b[r][jj].x);
                    b[r][jj].y = fmaf(dxv, (&ai.x)[jj], b[r][jj].y);
                }
            }
        }
#pragma unroll
        for (int r = 0; r < 4; ++r) {
            float* pa = buf0 + (i0 + r) * ROWF + j0 * 2;
            reinterpret_cast<float4*>(pa)[0] =
                make_float4(b[r][0].x, b[r][0].y, b[r][1].x, b[r][1].y);
            reinterpret_cast<float4*>(pa)[1] =
                make_float4(b[r][2].x, b[r][2].y, b[r][3].x, b[r][3].y);
        }
#pragma unroll
        for (int r = 0; r < 4; ++r)
#pragma unroll
            for (int jj = 0; jj < 4; ++jj) {
                const float2 btr =
                    reinterpret_cast<const float2*>(buf0 + (j0 + jj) * ROWF + (i0 + r) * 2)[0];
                a[r][jj].x = 0.5f * (b[r][jj].x - btr.x);
                a[r][jj].y = 0.5f * (b[r][jj].y + btr.y);
            }
    }

    // ---- induced 1-norm: max_j sum_i |AX[i,j]|
    float cs[4];
#pragma unroll
    for (int jj = 0; jj < 4; ++jj) {
        float s_ = 0.f;
#pragma unroll
        for (int r = 0; r < 4; ++r)
            s_ += sqrtf(a[r][jj].x * a[r][jj].x + a[r][jj].y * a[r][jj].y);
        cs[jj] = s_;
    }
#pragma unroll
    for (int jj = 0; jj < 4; ++jj) {
        cs[jj] += __shfl_xor(cs[jj], 4);
        cs[jj] += __shfl_xor(cs[jj], 8);
    }
    float mx = fmaxf(fmaxf(cs[0], cs[1]), fmaxf(cs[2], cs[3]));
    mx = fmaxf(mx, __shfl_xor(mx, 1));
    mx = fmaxf(mx, __shfl_xor(mx, 2));

    int s = 0;
    if (mx > 1.f) s = (int)ceilf(log2f(mx));
    if (s < 0) s = 0;
    if (s > 16) s = 16;
    const float scale = exp2f((float)(-s));
#pragma unroll
    for (int r = 0; r < 4; ++r)
#pragma unroll
        for (int jj = 0; jj < 4; ++jj) { a[r][jj].x *= scale; a[r][jj].y *= scale; }

    float2 cacc[4][4];

    auto zero_cacc = [&]() {
#pragma unroll
        for (int r = 0; r < 4; ++r)
#pragma unroll
            for (int jj = 0; jj < 4; ++jj) cacc[r][jj] = make_float2(0.f, 0.f);
    };

    // cacc += X @ Y, both in LDS. Per-kk granularity: 4x ds_read_b64 (X col)
    // + 2x ds_read_b128 (Y row) + 64 FMA; immediate offsets; ~16 live temps.
    auto matmul_lds = [&](const float* X, const float* Y) {
#pragma unroll 4
        for (int kk = 0; kk < 16; ++kk) {
            float2 xc[4];
#pragma unroll
            for (int r = 0; r < 4; ++r)
                xc[r] = *reinterpret_cast<const float2*>(X + (i0 + r) * ROWF + kk * 2);
            const float* py = Y + kk * ROWF + j0 * 2;
            const float4 y01 = reinterpret_cast<const float4*>(py)[0];
            const float4 y23 = reinterpret_cast<const float4*>(py)[1];
            const float2 yv[4] = { make_float2(y01.x, y01.y), make_float2(y01.z, y01.w),
                                   make_float2(y23.x, y23.y), make_float2(y23.z, y23.w) };
#pragma unroll
            for (int r = 0; r < 4; ++r)
#pragma unroll
                for (int jj = 0; jj < 4; ++jj) {
                    cacc[r][jj].x = fmaf(xc[r].x, yv[jj].x, cacc[r][jj].x);
                    cacc[r][jj].x = fmaf(-xc[r].y, yv[jj].y, cacc[r][jj].x);
                    cacc[r][jj].y = fmaf(xc[r].x, yv[jj].y, cacc[r][jj].y);
                    cacc[r][jj].y = fmaf(xc[r].y, yv[jj].x, cacc[r][jj].y);
                }
        }
    };

    float2 a2[4][4];   // Z = A1^2 tile (registers, lives through Horner)

    // cacc += X @ Z, X in LDS, Z gathered from holder lanes' a2 via __shfl.
    // Holder of Z[kk, j0+jj] is lane (t&48)|((kk>>2)*4+sj), element a2[kk&3][jj].
    // unroll 4 keeps kk&3 compile-time (a2 stays in registers).
    auto matmul_shfl_z = [&](const float* X) {
#pragma unroll 4
        for (int kk = 0; kk < 16; ++kk) {
            float2 xc[4];
#pragma unroll
            for (int r = 0; r < 4; ++r)
                xc[r] = *reinterpret_cast<const float2*>(X + (i0 + r) * ROWF + kk * 2);
            const int src = (t & 48) | ((kk >> 2) * 4 + sj);
            float2 zt[4];
#pragma unroll
            for (int jj = 0; jj < 4; ++jj) {
                zt[jj].x = __shfl(a2[kk & 3][jj].x, src);
                zt[jj].y = __shfl(a2[kk & 3][jj].y, src);
            }
#pragma unroll
            for (int r = 0; r < 4; ++r)
#pragma unroll
                for (int jj = 0; jj < 4; ++jj) {
                    cacc[r][jj].x = fmaf(xc[r].x, zt[jj].x, cacc[r][jj].x);
                    cacc[r][jj].x = fmaf(-xc[r].y, zt[jj].y, cacc[r][jj].x);
                    cacc[r][jj].y = fmaf(xc[r].x, zt[jj].y, cacc[r][jj].y);
                    cacc[r][jj].y = fmaf(xc[r].y, zt[jj].x, cacc[r][jj].y);
                }
        }
    };

    auto store_cacc = [&]() {
#pragma unroll
        for (int r = 0; r < 4; ++r) {
            float* p = buf0 + (i0 + r) * ROWF + j0 * 2;
            reinterpret_cast<float4*>(p)[0] =
                make_float4(cacc[r][0].x, cacc[r][0].y, cacc[r][1].x, cacc[r][1].y);
            reinterpret_cast<float4*>(p)[1] =
                make_float4(cacc[r][2].x, cacc[r][2].y, cacc[r][3].x, cacc[r][3].y);
        }
    };

    // ---- A1 -> buf0; Z = A1^2 -> cacc -> a2 (registers only)
#pragma unroll
    for (int r = 0; r < 4; ++r) {
        float* p = buf0 + (i0 + r) * ROWF + j0 * 2;
        reinterpret_cast<float4*>(p)[0] =
            make_float4(a[r][0].x, a[r][0].y, a[r][1].x, a[r][1].y);
        reinterpret_cast<float4*>(p)[1] =
            make_float4(a[r][2].x, a[r][2].y, a[r][3].x, a[r][3].y);
    }
    zero_cacc();
    matmul_lds(buf0, buf0);
#pragma unroll
    for (int r = 0; r < 4; ++r)
#pragma unroll
        for (int jj = 0; jj < 4; ++jj) a2[r][jj] = cacc[r][jj];

    // ---- leading PS block: T = C8*Z + C7*A + C6*I  (registers only)
#pragma unroll
    for (int r = 0; r < 4; ++r)
#pragma unroll
        for (int jj = 0; jj < 4; ++jj) {
            const float d = ((i0 + r) == (j0 + jj)) ? 1.f : 0.f;
            cacc[r][jj].x = C8 * a2[r][jj].x + C7 * a[r][jj].x + C6 * d;
            cacc[r][jj].y = C8 * a2[r][jj].y + C7 * a[r][jj].y;
        }

    // ---- 3 Horner steps: T <- T@Z + (cE*I + cO*A); Z via shuffle (no LDS buf)
    const float cE[3] = {C4, C2, C0};
    const float cO[3] = {C5, C3, C1};
#pragma unroll 1
    for (int h = 0; h < 3; ++h) {
        store_cacc();                    // T -> buf0
        const float e = cE[h], o = cO[h];
#pragma unroll
        for (int r = 0; r < 4; ++r)      // init accumulator with constant part
#pragma unroll
            for (int jj = 0; jj < 4; ++jj) {
                const float d = ((i0 + r) == (j0 + jj)) ? 1.f : 0.f;
                cacc[r][jj].x = o * a[r][jj].x + e * d;
                cacc[r][jj].y = o * a[r][jj].y;
            }
        matmul_shfl_z(buf0);
    }

    // ---- s squarings (per-group divergent trip count; LDS-only matmul)
#pragma unroll 1
    for (int step = 0; step < s; ++step) {
        store_cacc();
        zero_cacc();
        matmul_lds(buf0, buf0);
    }

    // ---- write result
    if (real_only) {
        float* po = out + (size_t)m * 256;
#pragma unroll
        for (int r = 0; r < 4; ++r)
            *reinterpret_cast<float4*>(po + (i0 + r) * 16 + j0) =
                make_float4(cacc[r][0].x, cacc[r][1].x, cacc[r][2].x, cacc[r][3].x);
    } else {
        float* po = out + (size_t)m * 512;
#pragma unroll
        for (int r = 0; r < 4; ++r) {
            float* p = po + ((i0 + r) * 16 + j0) * 2;
            reinterpret_cast<float4*>(p)[0] =
                make_float4(cacc[r][0].x, cacc[r][0].y, cacc[r][1].x, cacc[r][1].y);
            reinterpret_cast<float4*>(p)[1] =
                make_float4(cacc[r][2].x, cacc[r][2].y, cacc[r][3].x, cacc[r][3].y);
        }
    }
}

// ---------------------------------------------------------------------------
extern "C" void kernel_launch(void* const* d_in, const int* in_sizes, int n_in,
                              void* d_out, int out_size, void* d_ws, size_t ws_size,
                              hipStream_t stream)
{
    const float* dX = (const float*)d_in[0];
    const float* Ar = (const float*)d_in[1];
    const float* Ai = (const float*)d_in[2];
    float* out = (float*)d_out;
    float* ws  = (float*)d_ws;

    const int real_only = (out_size < NMAT * 512) ? 1 : 0;
    const size_t need = (size_t)NMAT * 512 * sizeof(float);
    const int use_ws = (ws_size >= need) ? 1 : 0;

    if (use_ws)
        hipLaunchKernelGGL(ax_kernel, dim3(NN / 8), dim3(256), 0, stream, dX, Ar, Ai, ws);
    hipLaunchKernelGGL(expm_kernel, dim3(NMAT / MPB), dim3(128), 0, stream,
                       dX, Ar, Ai, ws, out, use_ws, real_only);
}

// Round 8
// 388.973 us; speedup vs baseline: 1.0379x; 1.0379x over previous
//
#include <hip/hip_runtime.h>
#include <math.h>

// Problem constants
#define NN       16384
#define IN_DIM   64
#define CC       4
#define NMAT     (NN * CC)           // 65536 matrices
#define ROWF     36                  // floats per LDS row (16 complex + 2 pad)
#define BUFW     (16 * ROWF)         // 576 floats per buffer
#define MWORDS   (BUFW + 4)          // 580 floats per matrix region (4-bank stagger)
#define MPB      8                   // matrices per block (128 threads, 2 waves)

// Taylor coefficients 1/k!
#define C0 1.0f
#define C1 1.0f
#define C2 0.5f
#define C3 0.16666666666666666f
#define C4 0.041666666666666664f
#define C5 0.008333333333333333f
#define C6 0.001388888888888889f
#define C7 1.984126984126984e-4f
#define C8 2.48015873015873e-5f

// ---------------------------------------------------------------------------
// Phase 1 (ws path): B[n,c,i,j] = sum_k dX[n,k] * (Ar + i*Ai)[k,c,i,j]
// 8 n's per thread -> A-row loads amortized 8x. Fully coalesced stores.
// ---------------------------------------------------------------------------
__global__ __launch_bounds__(256)
void ax_kernel(const float* __restrict__ dX, const float* __restrict__ Ar,
               const float* __restrict__ Ai, float* __restrict__ ws)
{
    const int t  = threadIdx.x;
    const int nb = blockIdx.x * 8;         // 8 n's per block
    const int c  = t >> 6;
    const int i  = (t >> 2) & 15;
    const int j0 = (t & 3) * 4;

    float accre[8][4], accim[8][4];
#pragma unroll
    for (int nn_ = 0; nn_ < 8; ++nn_)
#pragma unroll
        for (int jj = 0; jj < 4; ++jj) { accre[nn_][jj] = 0.f; accim[nn_][jj] = 0.f; }

#pragma unroll 2
    for (int k = 0; k < IN_DIM; ++k) {
        const int base = (k * CC + c) * 256 + i * 16 + j0;
        const float4 ar = *reinterpret_cast<const float4*>(Ar + base);
        const float4 ai = *reinterpret_cast<const float4*>(Ai + base);
#pragma unroll
        for (int nn_ = 0; nn_ < 8; ++nn_) {
            const float dxv = dX[(nb + nn_) * IN_DIM + k];  // block-uniform -> s_load
#pragma unroll
            for (int jj = 0; jj < 4; ++jj) {
                accre[nn_][jj] = fmaf(dxv, (&ar.x)[jj], accre[nn_][jj]);
                accim[nn_][jj] = fmaf(dxv, (&ai.x)[jj], accim[nn_][jj]);
            }
        }
    }
#pragma unroll
    for (int nn_ = 0; nn_ < 8; ++nn_) {
        const int m = (nb + nn_) * CC + c;
        float* o = ws + (size_t)m * 512 + (i * 16 + j0) * 2;
        reinterpret_cast<float4*>(o)[0] =
            make_float4(accre[nn_][0], accim[nn_][0], accre[nn_][1], accim[nn_][1]);
        reinterpret_cast<float4*>(o)[1] =
            make_float4(accre[nn_][2], accim[nn_][2], accre[nn_][3], accim[nn_][3]);
    }
}

// ---------------------------------------------------------------------------
// Phase 2: per 16x16 complex matrix: skew-projection, 1-norm -> s, scale,
// expm via Paterson-Stockmeyer degree-8 (4 matmuls), then s squarings.
// One matrix per 16-lane group, 4x4 complex tile per lane. Single LDS buffer
// per matrix (18.9 KB/block -> 8 blocks/CU); Z in registers, Horner Y via
// __shfl. __launch_bounds__(128,2): empirically the 128-VGPR budget on this
// toolchain (r4: 124 VGPR no spill; r5/r6 with arg=4 / waves_per_eu(4,4):
// 64 VGPR + ~250 MB scratch spill traffic). 124 VGPR still allows 4
// waves/SIMD (512/124 -> 4), matching the LDS cap.
// All LDS traffic is per-lane-distinct and same-wave ordered (no barriers).
// ---------------------------------------------------------------------------
__global__ __launch_bounds__(128, 2)
void expm_kernel(const float* __restrict__ dX, const float* __restrict__ Ar,
                 const float* __restrict__ Ai, const float* __restrict__ ws,
                 float* __restrict__ out, const int use_ws, const int real_only)
{
    __shared__ __align__(16) float lds[MPB * MWORDS];

    const int t   = threadIdx.x;
    const int grp = t >> 4;
    const int sub = t & 15;
    const int si  = sub >> 2, sj = sub & 3;
    const int i0  = si * 4,  j0 = sj * 4;

    float* buf0 = lds + grp * MWORDS;   // the single per-matrix buffer

    const int m = blockIdx.x * MPB + grp;
    const int n = m >> 2;
    const int c = m & 3;

    // ---- obtain skew tile a[r][jj] = AX[i0+r, j0+jj] = 0.5*(B[i,j] - conj(B[j,i]))
    float2 a[4][4];
    if (use_ws) {
        const float* g = ws + (size_t)m * 512;
        float bs[4][8];   // straight rows:   bs[r][2t+e] = B[i0+r, j0+t].{re,im}
        float wf[4][8];   // transposed rows: wf[r][2t+e] = B[j0+r, i0+t].{re,im}
#pragma unroll
        for (int r = 0; r < 4; ++r) {
            *reinterpret_cast<float4*>(&bs[r][0]) =
                reinterpret_cast<const float4*>(g + ((i0 + r) * 16 + j0) * 2)[0];
            *reinterpret_cast<float4*>(&bs[r][4]) =
                reinterpret_cast<const float4*>(g + ((i0 + r) * 16 + j0) * 2)[1];
            *reinterpret_cast<float4*>(&wf[r][0]) =
                reinterpret_cast<const float4*>(g + ((j0 + r) * 16 + i0) * 2)[0];
            *reinterpret_cast<float4*>(&wf[r][4]) =
                reinterpret_cast<const float4*>(g + ((j0 + r) * 16 + i0) * 2)[1];
        }
        // register-only transpose: B[j0+jj, i0+r] = wf[jj][2r+e]  (compile-time idx)
#pragma unroll
        for (int r = 0; r < 4; ++r)
#pragma unroll
            for (int jj = 0; jj < 4; ++jj) {
                a[r][jj].x = 0.5f * (bs[r][2 * jj]     - wf[jj][2 * r]);
                a[r][jj].y = 0.5f * (bs[r][2 * jj + 1] + wf[jj][2 * r + 1]);
            }
    } else {
        // fused fallback: inline einsum for B tile + LDS transpose (per-lane-distinct)
        float2 b[4][4];
#pragma unroll
        for (int r = 0; r < 4; ++r)
#pragma unroll
            for (int jj = 0; jj < 4; ++jj) b[r][jj] = make_float2(0.f, 0.f);
        const float* dxp = dX + n * IN_DIM;
#pragma unroll 2
        for (int k = 0; k < IN_DIM; ++k) {
            const float dxv = dxp[k];
            const int base = (k * CC + c) * 256 + i0 * 16 + j0;
#pragma unroll
            for (int r = 0; r < 4; ++r) {
                const float4 ar = *reinterpret_cast<const float4*>(Ar + base + r * 16);
                const float4 ai = *reinterpret_cast<const float4*>(Ai + base + r * 16);
#pragma unroll
                for (int jj = 0; jj < 4; ++jj) {
                    b[r][jj].x = fmaf(dxv, (&ar.x)[jj], b[r][jj].x);
                    b[r][jj].y = fmaf(dxv, (&ai.x)[jj], b[r][jj].y);
                }
            }
        }
#pragma unroll
        for (int r = 0; r < 4; ++r) {
            float* pa = buf0 + (i0 + r) * ROWF + j0 * 2;
            reinterpret_cast<float4*>(pa)[0] =
                make_float4(b[r][0].x, b[r][0].y, b[r][1].x, b[r][1].y);
            reinterpret_cast<float4*>(pa)[1] =
                make_float4(b[r][2].x, b[r][2].y, b[r][3].x, b[r][3].y);
        }
#pragma unroll
        for (int r = 0; r < 4; ++r)
#pragma unroll
            for (int jj = 0; jj < 4; ++jj) {
                const float2 btr =
                    reinterpret_cast<const float2*>(buf0 + (j0 + jj) * ROWF + (i0 + r) * 2)[0];
                a[r][jj].x = 0.5f * (b[r][jj].x - btr.x);
                a[r][jj].y = 0.5f * (b[r][jj].y + btr.y);
            }
    }

    // ---- induced 1-norm: max_j sum_i |AX[i,j]|
    float cs[4];
#pragma unroll
    for (int jj = 0; jj < 4; ++jj) {
        float s_ = 0.f;
#pragma unroll
        for (int r = 0; r < 4; ++r)
            s_ += sqrtf(a[r][jj].x * a[r][jj].x + a[r][jj].y * a[r][jj].y);
        cs[jj] = s_;
    }
#pragma unroll
    for (int jj = 0; jj < 4; ++jj) {
        cs[jj] += __shfl_xor(cs[jj], 4);
        cs[jj] += __shfl_xor(cs[jj], 8);
    }
    float mx = fmaxf(fmaxf(cs[0], cs[1]), fmaxf(cs[2], cs[3]));
    mx = fmaxf(mx, __shfl_xor(mx, 1));
    mx = fmaxf(mx, __shfl_xor(mx, 2));

    int s = 0;
    if (mx > 1.f) s = (int)ceilf(log2f(mx));
    if (s < 0) s = 0;
    if (s > 16) s = 16;
    const float scale = exp2f((float)(-s));
#pragma unroll
    for (int r = 0; r < 4; ++r)
#pragma unroll
        for (int jj = 0; jj < 4; ++jj) { a[r][jj].x *= scale; a[r][jj].y *= scale; }

    float2 cacc[4][4];

    auto zero_cacc = [&]() {
#pragma unroll
        for (int r = 0; r < 4; ++r)
#pragma unroll
            for (int jj = 0; jj < 4; ++jj) cacc[r][jj] = make_float2(0.f, 0.f);
    };

    // cacc += X @ Y, both in LDS. Per-kk granularity: 4x ds_read_b64 (X col)
    // + 2x ds_read_b128 (Y row) + 64 FMA; immediate offsets; ~16 live temps.
    auto matmul_lds = [&](const float* X, const float* Y) {
#pragma unroll 4
        for (int kk = 0; kk < 16; ++kk) {
            float2 xc[4];
#pragma unroll
            for (int r = 0; r < 4; ++r)
                xc[r] = *reinterpret_cast<const float2*>(X + (i0 + r) * ROWF + kk * 2);
            const float* py = Y + kk * ROWF + j0 * 2;
            const float4 y01 = reinterpret_cast<const float4*>(py)[0];
            const float4 y23 = reinterpret_cast<const float4*>(py)[1];
            const float2 yv[4] = { make_float2(y01.x, y01.y), make_float2(y01.z, y01.w),
                                   make_float2(y23.x, y23.y), make_float2(y23.z, y23.w) };
#pragma unroll
            for (int r = 0; r < 4; ++r)
#pragma unroll
                for (int jj = 0; jj < 4; ++jj) {
                    cacc[r][jj].x = fmaf(xc[r].x, yv[jj].x, cacc[r][jj].x);
                    cacc[r][jj].x = fmaf(-xc[r].y, yv[jj].y, cacc[r][jj].x);
                    cacc[r][jj].y = fmaf(xc[r].x, yv[jj].y, cacc[r][jj].y);
                    cacc[r][jj].y = fmaf(xc[r].y, yv[jj].x, cacc[r][jj].y);
                }
        }
    };

    float2 a2[4][4];   // Z = A1^2 tile (registers, lives through Horner)

    // cacc += X @ Z, X in LDS, Z gathered from holder lanes' a2 via __shfl.
    // Holder of Z[kk, j0+jj] is lane (t&48)|((kk>>2)*4+sj), element a2[kk&3][jj].
    // unroll 4 keeps kk&3 compile-time (a2 stays in registers).
    auto matmul_shfl_z = [&](const float* X) {
#pragma unroll 4
        for (int kk = 0; kk < 16; ++kk) {
            float2 xc[4];
#pragma unroll
            for (int r = 0; r < 4; ++r)
                xc[r] = *reinterpret_cast<const float2*>(X + (i0 + r) * ROWF + kk * 2);
            const int src = (t & 48) | ((kk >> 2) * 4 + sj);
            float2 zt[4];
#pragma unroll
            for (int jj = 0; jj < 4; ++jj) {
                zt[jj].x = __shfl(a2[kk & 3][jj].x, src);
                zt[jj].y = __shfl(a2[kk & 3][jj].y, src);
            }
#pragma unroll
            for (int r = 0; r < 4; ++r)
#pragma unroll
                for (int jj = 0; jj < 4; ++jj) {
                    cacc[r][jj].x = fmaf(xc[r].x, zt[jj].x, cacc[r][jj].x);
                    cacc[r][jj].x = fmaf(-xc[r].y, zt[jj].y, cacc[r][jj].x);
                    cacc[r][jj].y = fmaf(xc[r].x, zt[jj].y, cacc[r][jj].y);
                    cacc[r][jj].y = fmaf(xc[r].y, zt[jj].x, cacc[r][jj].y);
                }
        }
    };

    auto store_cacc = [&]() {
#pragma unroll
        for (int r = 0; r < 4; ++r) {
            float* p = buf0 + (i0 + r) * ROWF + j0 * 2;
            reinterpret_cast<float4*>(p)[0] =
                make_float4(cacc[r][0].x, cacc[r][0].y, cacc[r][1].x, cacc[r][1].y);
            reinterpret_cast<float4*>(p)[1] =
                make_float4(cacc[r][2].x, cacc[r][2].y, cacc[r][3].x, cacc[r][3].y);
        }
    };

    // ---- A1 -> buf0; Z = A1^2 -> cacc -> a2 (registers only)
#pragma unroll
    for (int r = 0; r < 4; ++r) {
        float* p = buf0 + (i0 + r) * ROWF + j0 * 2;
        reinterpret_cast<float4*>(p)[0] =
            make_float4(a[r][0].x, a[r][0].y, a[r][1].x, a[r][1].y);
        reinterpret_cast<float4*>(p)[1] =
            make_float4(a[r][2].x, a[r][2].y, a[r][3].x, a[r][3].y);
    }
    zero_cacc();
    matmul_lds(buf0, buf0);
#pragma unroll
    for (int r = 0; r < 4; ++r)
#pragma unroll
        for (int jj = 0; jj < 4; ++jj) a2[r][jj] = cacc[r][jj];

    // ---- leading PS block: T = C8*Z + C7*A + C6*I  (registers only)
#pragma unroll
    for (int r = 0; r < 4; ++r)
#pragma unroll
        for (int jj = 0; jj < 4; ++jj) {
            const float d = ((i0 + r) == (j0 + jj)) ? 1.f : 0.f;
            cacc[r][jj].x = C8 * a2[r][jj].x + C7 * a[r][jj].x + C6 * d;
            cacc[r][jj].y = C8 * a2[r][jj].y + C7 * a[r][jj].y;
        }

    // ---- 3 Horner steps: T <- T@Z + (cE*I + cO*A); Z via shuffle (no LDS buf)
    const float cE[3] = {C4, C2, C0};
    const float cO[3] = {C5, C3, C1};
#pragma unroll 1
    for (int h = 0; h < 3; ++h) {
        store_cacc();                    // T -> buf0
        const float e = cE[h], o = cO[h];
#pragma unroll
        for (int r = 0; r < 4; ++r)      // init accumulator with constant part
#pragma unroll
            for (int jj = 0; jj < 4; ++jj) {
                const float d = ((i0 + r) == (j0 + jj)) ? 1.f : 0.f;
                cacc[r][jj].x = o * a[r][jj].x + e * d;
                cacc[r][jj].y = o * a[r][jj].y;
            }
        matmul_shfl_z(buf0);
    }

    // ---- s squarings (per-group divergent trip count; LDS-only matmul)
#pragma unroll 1
    for (int step = 0; step < s; ++step) {
        store_cacc();
        zero_cacc();
        matmul_lds(buf0, buf0);
    }

    // ---- write result
    if (real_only) {
        float* po = out + (size_t)m * 256;
#pragma unroll
        for (int r = 0; r < 4; ++r)
            *reinterpret_cast<float4*>(po + (i0 + r) * 16 + j0) =
                make_float4(cacc[r][0].x, cacc[r][1].x, cacc[r][2].x, cacc[r][3].x);
    } else {
        float* po = out + (size_t)m * 512;
#pragma unroll
        for (int r = 0; r < 4; ++r) {
            float* p = po + ((i0 + r) * 16 + j0) * 2;
            reinterpret_cast<float4*>(p)[0] =
                make_float4(cacc[r][0].x, cacc[r][0].y, cacc[r][1].x, cacc[r][1].y);
            reinterpret_cast<float4*>(p)[1] =
                make_float4(cacc[r][2].x, cacc[r][2].y, cacc[r][3].x, cacc[r][3].y);
        }
    }
}

// ---------------------------------------------------------------------------
extern "C" void kernel_launch(void* const* d_in, const int* in_sizes, int n_in,
                              void* d_out, int out_size, void* d_ws, size_t ws_size,
                              hipStream_t stream)
{
    const float* dX = (const float*)d_in[0];
    const float* Ar = (const float*)d_in[1];
    const float* Ai = (const float*)d_in[2];
    float* out = (float*)d_out;
    float* ws  = (float*)d_ws;

    const int real_only = (out_size < NMAT * 512) ? 1 : 0;
    const size_t need = (size_t)NMAT * 512 * sizeof(float);
    const int use_ws = (ws_size >= need) ? 1 : 0;

    if (use_ws)
        hipLaunchKernelGGL(ax_kernel, dim3(NN / 8), dim3(256), 0, stream, dX, Ar, Ai, ws);
    hipLaunchKernelGGL(expm_kernel, dim3(NMAT / MPB), dim3(128), 0, stream,
                       dX, Ar, Ai, ws, out, use_ws, real_only);
}

// Round 9
// 370.147 us; speedup vs baseline: 1.0907x; 1.0509x over previous
//
#include <hip/hip_runtime.h>
#include <math.h>

// Problem constants
#define NN       16384
#define IN_DIM   64
#define CC       4
#define NMAT     (NN * CC)           // 65536 matrices
#define ROWF     36                  // floats per LDS row (16 complex + 2 pad)
#define BUFW     (16 * ROWF)         // 576 floats per buffer
#define MWORDS   (BUFW + 4)          // 580 floats per matrix region (4-bank stagger)
#define MPB      8                   // matrices per block (128 threads, 2 waves)

// Taylor coefficients 1/k!
#define C0 1.0f
#define C1 1.0f
#define C2 0.5f
#define C3 0.16666666666666666f
#define C4 0.041666666666666664f
#define C5 0.008333333333333333f
#define C6 0.001388888888888889f
#define C7 1.984126984126984e-4f
#define C8 2.48015873015873e-5f

// ---------------------------------------------------------------------------
// Phase 1 (ws path): B[n,c,i,j] = sum_k dX[n,k] * (Ar + i*Ai)[k,c,i,j]
// ---------------------------------------------------------------------------
__global__ __launch_bounds__(256)
void ax_kernel(const float* __restrict__ dX, const float* __restrict__ Ar,
               const float* __restrict__ Ai, float* __restrict__ ws)
{
    const int t  = threadIdx.x;
    const int nb = blockIdx.x * 8;         // 8 n's per block
    const int c  = t >> 6;
    const int i  = (t >> 2) & 15;
    const int j0 = (t & 3) * 4;

    float accre[8][4], accim[8][4];
#pragma unroll
    for (int nn_ = 0; nn_ < 8; ++nn_)
#pragma unroll
        for (int jj = 0; jj < 4; ++jj) { accre[nn_][jj] = 0.f; accim[nn_][jj] = 0.f; }

#pragma unroll 2
    for (int k = 0; k < IN_DIM; ++k) {
        const int base = (k * CC + c) * 256 + i * 16 + j0;
        const float4 ar = *reinterpret_cast<const float4*>(Ar + base);
        const float4 ai = *reinterpret_cast<const float4*>(Ai + base);
#pragma unroll
        for (int nn_ = 0; nn_ < 8; ++nn_) {
            const float dxv = dX[(nb + nn_) * IN_DIM + k];  // block-uniform -> s_load
#pragma unroll
            for (int jj = 0; jj < 4; ++jj) {
                accre[nn_][jj] = fmaf(dxv, (&ar.x)[jj], accre[nn_][jj]);
                accim[nn_][jj] = fmaf(dxv, (&ai.x)[jj], accim[nn_][jj]);
            }
        }
    }
#pragma unroll
    for (int nn_ = 0; nn_ < 8; ++nn_) {
        const int m = (nb + nn_) * CC + c;
        float* o = ws + (size_t)m * 512 + (i * 16 + j0) * 2;
        reinterpret_cast<float4*>(o)[0] =
            make_float4(accre[nn_][0], accim[nn_][0], accre[nn_][1], accim[nn_][1]);
        reinterpret_cast<float4*>(o)[1] =
            make_float4(accre[nn_][2], accim[nn_][2], accre[nn_][3], accim[nn_][3]);
    }
}

// ---------------------------------------------------------------------------
// Phase 2: per 16x16 complex matrix: skew-projection, Z0 = A^2 (Hermitian),
// s from spectral bound ||A||_2 <= sqrt(||Z0||_1), scale in registers,
// expm via Paterson-Stockmeyer degree-8 (Z already computed!), s squarings.
// One matrix per 16-lane group, 4x4 complex tile per lane, single LDS buffer.
// __launch_bounds__(128) with NO min-waves arg: empirically the 2nd arg pins
// waves/SIMD to exactly that value on this toolchain (r4/r8: arg=2 -> occ 21%;
// r5/r6: waves_per_eu(4,4) -> occ 39% but 64-VGPR squeeze + spills). Uncapped:
// allocator picks ~r8's 88 VGPR (<=128 bucket) and scheduler can run 4/SIMD.
// All LDS traffic is per-lane-distinct and same-wave ordered (no barriers).
// ---------------------------------------------------------------------------
__global__ __launch_bounds__(128)
void expm_kernel(const float* __restrict__ dX, const float* __restrict__ Ar,
                 const float* __restrict__ Ai, const float* __restrict__ ws,
                 float* __restrict__ out, const int use_ws, const int real_only)
{
    __shared__ __align__(16) float lds[MPB * MWORDS];

    const int t   = threadIdx.x;
    const int grp = t >> 4;
    const int sub = t & 15;
    const int si  = sub >> 2, sj = sub & 3;
    const int i0  = si * 4,  j0 = sj * 4;

    float* buf0 = lds + grp * MWORDS;   // the single per-matrix buffer

    const int m = blockIdx.x * MPB + grp;
    const int n = m >> 2;
    const int c = m & 3;

    // ---- obtain skew tile a[r][jj] = AX[i0+r, j0+jj] = 0.5*(B[i,j] - conj(B[j,i]))
    float2 a[4][4];
    if (use_ws) {
        const float* g = ws + (size_t)m * 512;
        float bs[4][8];   // straight rows:   bs[r][2t+e] = B[i0+r, j0+t].{re,im}
        float wf[4][8];   // transposed rows: wf[r][2t+e] = B[j0+r, i0+t].{re,im}
#pragma unroll
        for (int r = 0; r < 4; ++r) {
            *reinterpret_cast<float4*>(&bs[r][0]) =
                reinterpret_cast<const float4*>(g + ((i0 + r) * 16 + j0) * 2)[0];
            *reinterpret_cast<float4*>(&bs[r][4]) =
                reinterpret_cast<const float4*>(g + ((i0 + r) * 16 + j0) * 2)[1];
            *reinterpret_cast<float4*>(&wf[r][0]) =
                reinterpret_cast<const float4*>(g + ((j0 + r) * 16 + i0) * 2)[0];
            *reinterpret_cast<float4*>(&wf[r][4]) =
                reinterpret_cast<const float4*>(g + ((j0 + r) * 16 + i0) * 2)[1];
        }
        // register-only transpose: B[j0+jj, i0+r] = wf[jj][2r+e]  (compile-time idx)
#pragma unroll
        for (int r = 0; r < 4; ++r)
#pragma unroll
            for (int jj = 0; jj < 4; ++jj) {
                a[r][jj].x = 0.5f * (bs[r][2 * jj]     - wf[jj][2 * r]);
                a[r][jj].y = 0.5f * (bs[r][2 * jj + 1] + wf[jj][2 * r + 1]);
            }
    } else {
        // fused fallback: inline einsum for B tile + LDS transpose (per-lane-distinct)
        float2 b[4][4];
#pragma unroll
        for (int r = 0; r < 4; ++r)
#pragma unroll
            for (int jj = 0; jj < 4; ++jj) b[r][jj] = make_float2(0.f, 0.f);
        const float* dxp = dX + n * IN_DIM;
#pragma unroll 2
        for (int k = 0; k < IN_DIM; ++k) {
            const float dxv = dxp[k];
            const int base = (k * CC + c) * 256 + i0 * 16 + j0;
#pragma unroll
            for (int r = 0; r < 4; ++r) {
                const float4 ar = *reinterpret_cast<const float4*>(Ar + base + r * 16);
                const float4 ai = *reinterpret_cast<const float4*>(Ai + base + r * 16);
#pragma unroll
                for (int jj = 0; jj < 4; ++jj) {
                    b[r][jj].x = fmaf(dxv, (&ar.x)[jj], b[r][jj].x);
                    b[r][jj].y = fmaf(dxv, (&ai.x)[jj], b[r][jj].y);
                }
            }
        }
#pragma unroll
        for (int r = 0; r < 4; ++r) {
            float* pa = buf0 + (i0 + r) * ROWF + j0 * 2;
            reinterpret_cast<float4*>(pa)[0] =
                make_float4(b[r][0].x, b[r][0].y, b[r][1].x, b[r][1].y);
            reinterpret_cast<float4*>(pa)[1] =
                make_float4(b[r][2].x, b[r][2].y, b[r][3].x, b[r][3].y);
        }
#pragma unroll
        for (int r = 0; r < 4; ++r)
#pragma unroll
            for (int jj = 0; jj < 4; ++jj) {
                const float2 btr =
                    reinterpret_cast<const float2*>(buf0 + (j0 + jj) * ROWF + (i0 + r) * 2)[0];
                a[r][jj].x = 0.5f * (b[r][jj].x - btr.x);
                a[r][jj].y = 0.5f * (b[r][jj].y + btr.y);
            }
    }

    float2 cacc[4][4];

    auto zero_cacc = [&]() {
#pragma unroll
        for (int r = 0; r < 4; ++r)
#pragma unroll
            for (int jj = 0; jj < 4; ++jj) cacc[r][jj] = make_float2(0.f, 0.f);
    };

    // cacc += X @ Y, both in LDS. Per-kk: 4x ds_read_b64 (X col) + 2x
    // ds_read_b128 (Y row) + 64 FMA; immediate offsets. Full unroll: lets the
    // scheduler hoist next-kk reads under current-kk FMAs.
    auto matmul_lds = [&](const float* X, const float* Y) {
#pragma unroll
        for (int kk = 0; kk < 16; ++kk) {
            float2 xc[4];
#pragma unroll
            for (int r = 0; r < 4; ++r)
                xc[r] = *reinterpret_cast<const float2*>(X + (i0 + r) * ROWF + kk * 2);
            const float* py = Y + kk * ROWF + j0 * 2;
            const float4 y01 = reinterpret_cast<const float4*>(py)[0];
            const float4 y23 = reinterpret_cast<const float4*>(py)[1];
            const float2 yv[4] = { make_float2(y01.x, y01.y), make_float2(y01.z, y01.w),
                                   make_float2(y23.x, y23.y), make_float2(y23.z, y23.w) };
#pragma unroll
            for (int r = 0; r < 4; ++r)
#pragma unroll
                for (int jj = 0; jj < 4; ++jj) {
                    cacc[r][jj].x = fmaf(xc[r].x, yv[jj].x, cacc[r][jj].x);
                    cacc[r][jj].x = fmaf(-xc[r].y, yv[jj].y, cacc[r][jj].x);
                    cacc[r][jj].y = fmaf(xc[r].x, yv[jj].y, cacc[r][jj].y);
                    cacc[r][jj].y = fmaf(xc[r].y, yv[jj].x, cacc[r][jj].y);
                }
        }
    };

    float2 a2[4][4];   // Z = A1^2 tile (registers, lives through Horner)

    // cacc += X @ Z, X in LDS, Z gathered from holder lanes' a2 via __shfl.
    // Holder of Z[kk, j0+jj] is lane (t&48)|((kk>>2)*4+sj), element a2[kk&3][jj].
    auto matmul_shfl_z = [&](const float* X) {
#pragma unroll
        for (int kk = 0; kk < 16; ++kk) {
            float2 xc[4];
#pragma unroll
            for (int r = 0; r < 4; ++r)
                xc[r] = *reinterpret_cast<const float2*>(X + (i0 + r) * ROWF + kk * 2);
            const int src = (t & 48) | ((kk >> 2) * 4 + sj);
            float2 zt[4];
#pragma unroll
            for (int jj = 0; jj < 4; ++jj) {
                zt[jj].x = __shfl(a2[kk & 3][jj].x, src);
                zt[jj].y = __shfl(a2[kk & 3][jj].y, src);
            }
#pragma unroll
            for (int r = 0; r < 4; ++r)
#pragma unroll
                for (int jj = 0; jj < 4; ++jj) {
                    cacc[r][jj].x = fmaf(xc[r].x, zt[jj].x, cacc[r][jj].x);
                    cacc[r][jj].x = fmaf(-xc[r].y, zt[jj].y, cacc[r][jj].x);
                    cacc[r][jj].y = fmaf(xc[r].x, zt[jj].y, cacc[r][jj].y);
                    cacc[r][jj].y = fmaf(xc[r].y, zt[jj].x, cacc[r][jj].y);
                }
        }
    };

    auto store_cacc = [&]() {
#pragma unroll
        for (int r = 0; r < 4; ++r) {
            float* p = buf0 + (i0 + r) * ROWF + j0 * 2;
            reinterpret_cast<float4*>(p)[0] =
                make_float4(cacc[r][0].x, cacc[r][0].y, cacc[r][1].x, cacc[r][1].y);
            reinterpret_cast<float4*>(p)[1] =
                make_float4(cacc[r][2].x, cacc[r][2].y, cacc[r][3].x, cacc[r][3].y);
        }
    };

    // ---- unscaled A -> buf0; Z0 = A^2 -> cacc
#pragma unroll
    for (int r = 0; r < 4; ++r) {
        float* p = buf0 + (i0 + r) * ROWF + j0 * 2;
        reinterpret_cast<float4*>(p)[0] =
            make_float4(a[r][0].x, a[r][0].y, a[r][1].x, a[r][1].y);
        reinterpret_cast<float4*>(p)[1] =
            make_float4(a[r][2].x, a[r][2].y, a[r][3].x, a[r][3].y);
    }
    zero_cacc();
    matmul_lds(buf0, buf0);

    // ---- s from spectral bound: ||A||_2^2 = ||Z0||_2 <= ||Z0||_1 (Z0 Hermitian)
    float cs[4];
#pragma unroll
    for (int jj = 0; jj < 4; ++jj) {
        float s_ = 0.f;
#pragma unroll
        for (int r = 0; r < 4; ++r)
            s_ += sqrtf(cacc[r][jj].x * cacc[r][jj].x + cacc[r][jj].y * cacc[r][jj].y);
        cs[jj] = s_;
    }
#pragma unroll
    for (int jj = 0; jj < 4; ++jj) {   // reduce over si (lane bits 2,3)
        cs[jj] += __shfl_xor(cs[jj], 4);
        cs[jj] += __shfl_xor(cs[jj], 8);
    }
    float nz = fmaxf(fmaxf(cs[0], cs[1]), fmaxf(cs[2], cs[3]));
    nz = fmaxf(nz, __shfl_xor(nz, 1));  // max over sj (lane bits 0,1)
    nz = fmaxf(nz, __shfl_xor(nz, 2));

    int s = 0;
    if (nz > 1.f) s = (int)ceilf(0.5f * log2f(nz));
    if (s < 0) s = 0;
    if (s > 16) s = 16;
    const float sc1 = exp2f((float)(-s));        // 2^-s  for A
    const float sc2 = sc1 * sc1;                 // 2^-2s for Z0

    // ---- scale in registers: a <- A1 tile, a2 <- Z = A1^2 tile
#pragma unroll
    for (int r = 0; r < 4; ++r)
#pragma unroll
        for (int jj = 0; jj < 4; ++jj) {
            a[r][jj].x  *= sc1;  a[r][jj].y  *= sc1;
            a2[r][jj].x = cacc[r][jj].x * sc2;
            a2[r][jj].y = cacc[r][jj].y * sc2;
        }

    // ---- leading PS block: T = C8*Z + C7*A + C6*I  (registers only)
#pragma unroll
    for (int r = 0; r < 4; ++r)
#pragma unroll
        for (int jj = 0; jj < 4; ++jj) {
            const float d = ((i0 + r) == (j0 + jj)) ? 1.f : 0.f;
            cacc[r][jj].x = C8 * a2[r][jj].x + C7 * a[r][jj].x + C6 * d;
            cacc[r][jj].y = C8 * a2[r][jj].y + C7 * a[r][jj].y;
        }

    // ---- 3 Horner steps: T <- T@Z + (cE*I + cO*A); Z via shuffle (no LDS buf)
    const float cE[3] = {C4, C2, C0};
    const float cO[3] = {C5, C3, C1};
#pragma unroll 1
    for (int h = 0; h < 3; ++h) {
        store_cacc();                    // T -> buf0
        const float e = cE[h], o = cO[h];
#pragma unroll
        for (int r = 0; r < 4; ++r)      // init accumulator with constant part
#pragma unroll
            for (int jj = 0; jj < 4; ++jj) {
                const float d = ((i0 + r) == (j0 + jj)) ? 1.f : 0.f;
                cacc[r][jj].x = o * a[r][jj].x + e * d;
                cacc[r][jj].y = o * a[r][jj].y;
            }
        matmul_shfl_z(buf0);
    }

    // ---- s squarings (per-group divergent trip count; LDS-only matmul)
#pragma unroll 1
    for (int step = 0; step < s; ++step) {
        store_cacc();
        zero_cacc();
        matmul_lds(buf0, buf0);
    }

    // ---- write result
    if (real_only) {
        float* po = out + (size_t)m * 256;
#pragma unroll
        for (int r = 0; r < 4; ++r)
            *reinterpret_cast<float4*>(po + (i0 + r) * 16 + j0) =
                make_float4(cacc[r][0].x, cacc[r][1].x, cacc[r][2].x, cacc[r][3].x);
    } else {
        float* po = out + (size_t)m * 512;
#pragma unroll
        for (int r = 0; r < 4; ++r) {
            float* p = po + ((i0 + r) * 16 + j0) * 2;
            reinterpret_cast<float4*>(p)[0] =
                make_float4(cacc[r][0].x, cacc[r][0].y, cacc[r][1].x, cacc[r][1].y);
            reinterpret_cast<float4*>(p)[1] =
                make_float4(cacc[r][2].x, cacc[r][2].y, cacc[r][3].x, cacc[r][3].y);
        }
    }
}

// ---------------------------------------------------------------------------
extern "C" void kernel_launch(void* const* d_in, const int* in_sizes, int n_in,
                              void* d_out, int out_size, void* d_ws, size_t ws_size,
                              hipStream_t stream)
{
    const float* dX = (const float*)d_in[0];
    const float* Ar = (const float*)d_in[1];
    const float* Ai = (const float*)d_in[2];
    float* out = (float*)d_out;
    float* ws  = (float*)d_ws;

    const int real_only = (out_size < NMAT * 512) ? 1 : 0;
    const size_t need = (size_t)NMAT * 512 * sizeof(float);
    const int use_ws = (ws_size >= need) ? 1 : 0;

    if (use_ws)
        hipLaunchKernelGGL(ax_kernel, dim3(NN / 8), dim3(256), 0, stream, dX, Ar, Ai, ws);
    hipLaunchKernelGGL(expm_kernel, dim3(NMAT / MPB), dim3(128), 0, stream,
                       dX, Ar, Ai, ws, out, use_ws, real_only);
}

// Round 10
// 258.321 us; speedup vs baseline: 1.5628x; 1.4329x over previous
//
#include <hip/hip_runtime.h>
#include <math.h>

// Problem constants
#define NN       16384
#define IN_DIM   64
#define CC       4
#define NMAT     (NN * CC)

// Taylor coefficients 1/k!
#define C0 1.0f
#define C1 1.0f
#define C2 0.5f
#define C3 0.16666666666666666f
#define C4 0.041666666666666664f
#define C5 0.008333333333333333f
#define C6 0.001388888888888889f
#define C7 1.984126984126984e-4f
#define C8 2.48015873015873e-5f

typedef __attribute__((ext_vector_type(8))) short bf16x8;   // 8 bf16 = 4 VGPR
typedef __attribute__((ext_vector_type(4))) float f32x4;    // C/D frag

#define MFMA16(A, B, C) __builtin_amdgcn_mfma_f32_16x16x32_bf16((A), (B), (C), 0, 0, 0)

// Per-matrix LDS region (bytes):
//  colmaj planes (B-operand): XH@0, YH@768, XL@1536, YL@2304; col stride 48B
//  rowmaj planes (A-operand): base 3072: XH@0, YH@768, XL@1536, YL@2304; row stride 48B
#define COLP   768
#define ROWB   3072
#define MATB   6144
#define WPB    4              // 4 waves (matrices) per 256-thread block

__device__ __forceinline__ unsigned hi16(float x) {
    return __builtin_bit_cast(unsigned, x) >> 16;
}
__device__ __forceinline__ float hif(float x) {
    return __builtin_bit_cast(float, __builtin_bit_cast(unsigned, x) & 0xFFFF0000u);
}
__device__ __forceinline__ unsigned pk2(float a, float b) {   // bf16(a) | bf16(b)<<16 (truncation)
    return (__builtin_bit_cast(unsigned, a) >> 16) |
           (__builtin_bit_cast(unsigned, b) & 0xFFFF0000u);
}

// ---------------------------------------------------------------------------
// Phase 1: B[n,c,i,j] = sum_k dX[n,k] * (Ar + i*Ai)[k,c,i,j]  -> ws (interleaved)
// ---------------------------------------------------------------------------
__global__ __launch_bounds__(256)
void ax_kernel(const float* __restrict__ dX, const float* __restrict__ Ar,
               const float* __restrict__ Ai, float* __restrict__ ws)
{
    const int t  = threadIdx.x;
    const int nb = blockIdx.x * 8;
    const int c  = t >> 6;
    const int i  = (t >> 2) & 15;
    const int j0 = (t & 3) * 4;

    float accre[8][4], accim[8][4];
#pragma unroll
    for (int nn_ = 0; nn_ < 8; ++nn_)
#pragma unroll
        for (int jj = 0; jj < 4; ++jj) { accre[nn_][jj] = 0.f; accim[nn_][jj] = 0.f; }

#pragma unroll 2
    for (int k = 0; k < IN_DIM; ++k) {
        const int base = (k * CC + c) * 256 + i * 16 + j0;
        const float4 ar = *reinterpret_cast<const float4*>(Ar + base);
        const float4 ai = *reinterpret_cast<const float4*>(Ai + base);
#pragma unroll
        for (int nn_ = 0; nn_ < 8; ++nn_) {
            const float dxv = dX[(nb + nn_) * IN_DIM + k];
#pragma unroll
            for (int jj = 0; jj < 4; ++jj) {
                accre[nn_][jj] = fmaf(dxv, (&ar.x)[jj], accre[nn_][jj]);
                accim[nn_][jj] = fmaf(dxv, (&ai.x)[jj], accim[nn_][jj]);
            }
        }
    }
#pragma unroll
    for (int nn_ = 0; nn_ < 8; ++nn_) {
        const int m = (nb + nn_) * CC + c;
        float* o = ws + (size_t)m * 512 + (i * 16 + j0) * 2;
        reinterpret_cast<float4*>(o)[0] =
            make_float4(accre[nn_][0], accim[nn_][0], accre[nn_][1], accim[nn_][1]);
        reinterpret_cast<float4*>(o)[1] =
            make_float4(accre[nn_][2], accim[nn_][2], accre[nn_][3], accim[nn_][3]);
    }
}

// ---------------------------------------------------------------------------
// Phase 2 (MFMA): one 16x16 complex matrix per wave.
// Complex 16x16x16 product as ONE K=32 mfma pair:
//   A = [X | Y] along k;  B1 = [Xb ; -Yb] -> Re;  B2 = [Yb ; Xb] -> Im.
// f32 precision via bf16 hi/lo split, 3 term-products per output.
// C/D layout (HW-verified): col = lane&15, row = (lane>>4)*4 + q.
// A/B frag (standard CDNA): A row = lane&15, k = 8*(lane>>4)+j; B col = lane&15,
// same k map — any common k-order is correct by commutativity of the k-sum.
// LDS: per-matrix colmaj (B reads, b128) + rowmaj 48B-stride (A reads, b128);
// wave-private regions -> no barriers (same-wave DS ordering).
// ---------------------------------------------------------------------------
__global__ __launch_bounds__(256)
void expm_mfma_kernel(const float* __restrict__ dX, const float* __restrict__ Ar,
                      const float* __restrict__ Ai, const float* __restrict__ ws,
                      float* __restrict__ out, const int use_ws, const int real_only)
{
    __shared__ __align__(16) unsigned char ldsraw[WPB * MATB];

    const int t = threadIdx.x;
    const int w = t >> 6;          // wave in block
    const int l = t & 63;          // lane
    unsigned char* L = ldsraw + w * MATB;

    const int m  = blockIdx.x * WPB + w;     // matrix index
    const int n  = m >> 2;
    const int cc = m & 3;

    const int c     = l & 15;      // owned column (C/D); also A-frag row
    const int g     = l >> 4;      // row-group (C/D rows 4g..4g+3)
    const int ghalf = g & 1;
    const int gsel  = g >> 1;      // 0: lanes 0-31 (k<16 = X), 1: lanes 32-63 (k>=16 = Y)

    // byte offsets inside the matrix region
    const int colent  = c * 48 + ghalf * 16;
    const int off_B1h = (gsel ? COLP : 0) + colent;          // X then Y (negated)
    const int off_B2h = (gsel ? 0 : COLP) + colent;          // Y then X
    const int off_Ah  = ROWB + (gsel ? COLP : 0) + colent;   // A: row = c, k-slice
    const int wc      = c * 48 + g * 8;                      // colmaj write (4 bf16)

    const short ns = gsel ? (short)0x8000 : (short)0;
    const bf16x8 negv = {ns, ns, ns, ns, ns, ns, ns, ns};

    float dq[4];
#pragma unroll
    for (int q = 0; q < 4; ++q) dq[q] = ((4 * g + q) == c) ? 1.f : 0.f;

    // ---- load AX tile (C/D ownership) + transposed values; skew-project
    float aRe[4], aIm[4];
    if (use_ws) {
        const float* gp = ws + (size_t)m * 512;
#pragma unroll
        for (int q = 0; q < 4; ++q) {
            const int r = 4 * g + q;
            const float2 v = *reinterpret_cast<const float2*>(gp + (r * 16 + c) * 2);
            const float2 u = *reinterpret_cast<const float2*>(gp + (c * 16 + r) * 2);
            aRe[q] = 0.5f * (v.x - u.x);
            aIm[q] = 0.5f * (v.y + u.y);
        }
    } else {
        // slow fallback: direct einsum (defensive; ws path is the real one)
        float bRe[4] = {0,0,0,0}, bIm[4] = {0,0,0,0}, uRe[4] = {0,0,0,0}, uIm[4] = {0,0,0,0};
        for (int k = 0; k < IN_DIM; ++k) {
            const float dxv = dX[n * IN_DIM + k];
            const int base = (k * CC + cc) * 256;
#pragma unroll
            for (int q = 0; q < 4; ++q) {
                const int r = 4 * g + q;
                bRe[q] = fmaf(dxv, Ar[base + r * 16 + c], bRe[q]);
                bIm[q] = fmaf(dxv, Ai[base + r * 16 + c], bIm[q]);
                uRe[q] = fmaf(dxv, Ar[base + c * 16 + r], uRe[q]);
                uIm[q] = fmaf(dxv, Ai[base + c * 16 + r], uIm[q]);
            }
        }
#pragma unroll
        for (int q = 0; q < 4; ++q) {
            aRe[q] = 0.5f * (bRe[q] - uRe[q]);
            aIm[q] = 0.5f * (bIm[q] + uIm[q]);
        }
    }

    // ---- reference norm: max_j sum_i |AX[i,j]|  (lane owns 4 rows of col c)
    float colsum = 0.f;
#pragma unroll
    for (int q = 0; q < 4; ++q)
        colsum += sqrtf(aRe[q] * aRe[q] + aIm[q] * aIm[q]);
    colsum += __shfl_xor(colsum, 16);
    colsum += __shfl_xor(colsum, 32);
    float mx = colsum;
    mx = fmaxf(mx, __shfl_xor(mx, 1));
    mx = fmaxf(mx, __shfl_xor(mx, 2));
    mx = fmaxf(mx, __shfl_xor(mx, 4));
    mx = fmaxf(mx, __shfl_xor(mx, 8));

    int s = 0;
    if (mx > 1.f) s = (int)ceilf(log2f(mx));
    if (s < 0) s = 0;
    if (s > 16) s = 16;
    const float sc = exp2f((float)(-s));
#pragma unroll
    for (int q = 0; q < 4; ++q) { aRe[q] *= sc; aIm[q] *= sc; }

    // ---- helpers -----------------------------------------------------------
    // write current values (C/D layout) to colmaj planes (b64 each)
    auto wcol = [&](const float* vR, const float* vI) {
        uint2 xh, yh, xl, yl;
        xh.x = pk2(vR[0], vR[1]); xh.y = pk2(vR[2], vR[3]);
        yh.x = pk2(vI[0], vI[1]); yh.y = pk2(vI[2], vI[3]);
        float l0 = vR[0] - hif(vR[0]), l1 = vR[1] - hif(vR[1]);
        float l2 = vR[2] - hif(vR[2]), l3 = vR[3] - hif(vR[3]);
        xl.x = pk2(l0, l1); xl.y = pk2(l2, l3);
        l0 = vI[0] - hif(vI[0]); l1 = vI[1] - hif(vI[1]);
        l2 = vI[2] - hif(vI[2]); l3 = vI[3] - hif(vI[3]);
        yl.x = pk2(l0, l1); yl.y = pk2(l2, l3);
        *reinterpret_cast<uint2*>(L + 0    + wc) = xh;
        *reinterpret_cast<uint2*>(L + COLP + wc) = yh;
        *reinterpret_cast<uint2*>(L + 1536 + wc) = xl;
        *reinterpret_cast<uint2*>(L + 2304 + wc) = yl;
    };
    // write to rowmaj planes (scattered b16; bank-spread by 48B row stride)
    auto wrow = [&](const float* vR, const float* vI) {
#pragma unroll
        for (int q = 0; q < 4; ++q) {
            const int rb = ROWB + (4 * g + q) * 48 + c * 2;
            *reinterpret_cast<unsigned short*>(L + rb + 0)    = (unsigned short)hi16(vR[q]);
            *reinterpret_cast<unsigned short*>(L + rb + COLP) = (unsigned short)hi16(vI[q]);
            const float lr = vR[q] - hif(vR[q]);
            const float li = vI[q] - hif(vI[q]);
            *reinterpret_cast<unsigned short*>(L + rb + 1536) = (unsigned short)hi16(lr);
            *reinterpret_cast<unsigned short*>(L + rb + 2304) = (unsigned short)hi16(li);
        }
    };
    // complex mfma: acc += M(A) * M(B) with A-frags given, B from colmaj
    auto cmul = [&](const bf16x8 Ah, const bf16x8 Al, f32x4& accRe, f32x4& accIm) {
        bf16x8 b1h = *reinterpret_cast<const bf16x8*>(L + off_B1h);
        bf16x8 b1l = *reinterpret_cast<const bf16x8*>(L + off_B1h + 1536);
        const bf16x8 b2h = *reinterpret_cast<const bf16x8*>(L + off_B2h);
        const bf16x8 b2l = *reinterpret_cast<const bf16x8*>(L + off_B2h + 1536);
        b1h ^= negv;                 // -Yb on the k>=16 half
        b1l ^= negv;
        accRe = MFMA16(Ah, b1h, accRe);
        accRe = MFMA16(Ah, b1l, accRe);
        accRe = MFMA16(Al, b1h, accRe);
        accIm = MFMA16(Ah, b2h, accIm);
        accIm = MFMA16(Ah, b2l, accIm);
        accIm = MFMA16(Al, b2h, accIm);
    };

    // ---- A1 -> colmaj + rowmaj; Z = A1^2
    wcol(aRe, aIm);
    wrow(aRe, aIm);
    bf16x8 Ah = *reinterpret_cast<const bf16x8*>(L + off_Ah);
    bf16x8 Al = *reinterpret_cast<const bf16x8*>(L + off_Ah + 1536);
    f32x4 zr4 = {0.f, 0.f, 0.f, 0.f}, zi4 = {0.f, 0.f, 0.f, 0.f};
    cmul(Ah, Al, zr4, zi4);

    float zr[4], zi[4];
#pragma unroll
    for (int q = 0; q < 4; ++q) { zr[q] = zr4[q]; zi[q] = zi4[q]; }
    wrow(zr, zi);                                 // Z used only as A-operand
    const bf16x8 ZAh = *reinterpret_cast<const bf16x8*>(L + off_Ah);
    const bf16x8 ZAl = *reinterpret_cast<const bf16x8*>(L + off_Ah + 1536);

    // ---- T = C8*Z + C7*A + C6*I
    float tRe[4], tIm[4];
#pragma unroll
    for (int q = 0; q < 4; ++q) {
        tRe[q] = C8 * zr[q] + C7 * aRe[q] + C6 * dq[q];
        tIm[q] = C8 * zi[q] + C7 * aIm[q];
    }

    // ---- 3 Horner steps: T <- Z*T + (cE*I + cO*A)   (Z,T commute)
    const float cE[3] = {C4, C2, C0};
    const float cO[3] = {C5, C3, C1};
#pragma unroll
    for (int h = 0; h < 3; ++h) {
        wcol(tRe, tIm);                           // T as B-operand
        f32x4 rr, ri;
#pragma unroll
        for (int q = 0; q < 4; ++q) {
            rr[q] = cO[h] * aRe[q] + cE[h] * dq[q];
            ri[q] = cO[h] * aIm[q];
        }
        cmul(ZAh, ZAl, rr, ri);
#pragma unroll
        for (int q = 0; q < 4; ++q) { tRe[q] = rr[q]; tIm[q] = ri[q]; }
    }

    // ---- s squarings (s is wave-uniform -> divergence-free)
#pragma unroll 1
    for (int it = 0; it < s; ++it) {
        wcol(tRe, tIm);
        wrow(tRe, tIm);
        const bf16x8 Ph = *reinterpret_cast<const bf16x8*>(L + off_Ah);
        const bf16x8 Pl = *reinterpret_cast<const bf16x8*>(L + off_Ah + 1536);
        f32x4 rr = {0.f, 0.f, 0.f, 0.f}, ri = {0.f, 0.f, 0.f, 0.f};
        cmul(Ph, Pl, rr, ri);
#pragma unroll
        for (int q = 0; q < 4; ++q) { tRe[q] = rr[q]; tIm[q] = ri[q]; }
    }

    // ---- write result
    if (real_only) {
        float* po = out + (size_t)m * 256;
#pragma unroll
        for (int q = 0; q < 4; ++q)
            po[(4 * g + q) * 16 + c] = tRe[q];
    } else {
        float* po = out + (size_t)m * 512;
#pragma unroll
        for (int q = 0; q < 4; ++q)
            *reinterpret_cast<float2*>(po + ((4 * g + q) * 16 + c) * 2) =
                make_float2(tRe[q], tIm[q]);
    }
}

// ---------------------------------------------------------------------------
extern "C" void kernel_launch(void* const* d_in, const int* in_sizes, int n_in,
                              void* d_out, int out_size, void* d_ws, size_t ws_size,
                              hipStream_t stream)
{
    const float* dX = (const float*)d_in[0];
    const float* Ar = (const float*)d_in[1];
    const float* Ai = (const float*)d_in[2];
    float* out = (float*)d_out;
    float* ws  = (float*)d_ws;

    const int real_only = (out_size < NMAT * 512) ? 1 : 0;
    const size_t need = (size_t)NMAT * 512 * sizeof(float);
    const int use_ws = (ws_size >= need) ? 1 : 0;

    if (use_ws)
        hipLaunchKernelGGL(ax_kernel, dim3(NN / 8), dim3(256), 0, stream, dX, Ar, Ai, ws);
    hipLaunchKernelGGL(expm_mfma_kernel, dim3(NMAT / WPB), dim3(256), 0, stream,
                       dX, Ar, Ai, ws, out, use_ws, real_only);
}